// Round 2
// baseline (335.337 us; speedup 1.0000x reference)
//
#include <hip/hip_runtime.h>
#include <hip/hip_bf16.h>

// out[i][j] = ||x_i - y_j||, x:[4096,256] f32, y:[16384,256] f32, out:[4096,16384] f32
// d2 = x2 + y2 - 2<x,y>; cross term via bf16 MFMA.
// Round 2: pre-convert x,y to bf16 once (prep kernel), stage via global_load_lds
// width=16 with XOR-swizzled LDS layout (no padding needed), transposed MFMA roles
// so the epilogue stores float4 along y.

using bf16x8 = __attribute__((ext_vector_type(8))) short;
using f32x4  = __attribute__((ext_vector_type(4))) float;

constexpr int NXR = 4096;    // rows of x
constexpr int NYR = 16384;   // rows of y
constexpr int DD  = 256;     // feature dim

constexpr int BT = 128;      // output tile edge (both dims)
constexpr int BK = 128;      // K slice (bf16 elements) per stage; 2 stages cover DD

__device__ inline unsigned short f2bf(float f) {
    unsigned int b = __float_as_uint(f);
    b += 0x7FFFu + ((b >> 16) & 1u);   // RNE
    return (unsigned short)(b >> 16);
}

#define GLDS(gp, lp) __builtin_amdgcn_global_load_lds(                      \
    (const __attribute__((address_space(1))) void*)(gp),                    \
    (__attribute__((address_space(3))) void*)(lp), 16, 0, 0)

// ---------------- prep: bf16 copies + row norms. One wave per row.
__global__ __launch_bounds__(256) void prep_kernel(const float* __restrict__ x,
                                                   const float* __restrict__ y,
                                                   unsigned short* __restrict__ xb,
                                                   unsigned short* __restrict__ yb,
                                                   float* __restrict__ xn,
                                                   float* __restrict__ yn) {
    const int row  = blockIdx.x * 4 + (threadIdx.x >> 6);
    const int lane = threadIdx.x & 63;
    const bool isx = row < NXR;
    const int r    = isx ? row : row - NXR;
    const float* src = (isx ? x : y) + (size_t)r * DD;
    float4 v = *(const float4*)(src + lane * 4);
    ushort4 u = { f2bf(v.x), f2bf(v.y), f2bf(v.z), f2bf(v.w) };
    unsigned short* dst = (isx ? xb : yb) + (size_t)r * DD;
    *(ushort4*)(dst + lane * 4) = u;
    float s = v.x * v.x + v.y * v.y + v.z * v.z + v.w * v.w;
    #pragma unroll
    for (int off = 32; off > 0; off >>= 1) s += __shfl_down(s, off, 64);
    if (lane == 0) { if (isx) xn[r] = s; else yn[r] = s; }
}

// ---------------- main distance kernel
// MFMA roles: A-operand = y tile (M dim = y rows), B-operand = x tile (N = x rows).
// D layout (16x16x32, verified m89): n-col = lane&15 -> x row; m-row = quad*4+reg -> y row.
// => each lane's 4 acc regs are 4 consecutive y columns: float4 store.
__global__ __launch_bounds__(512) void dist_kernel(const unsigned short* __restrict__ xb,
                                                   const unsigned short* __restrict__ yb,
                                                   const float* __restrict__ xn,
                                                   const float* __restrict__ yn,
                                                   float* __restrict__ out) {
    __shared__ unsigned short lY[BT * BK];   // 32 KB, A/M tile
    __shared__ unsigned short lX[BT * BK];   // 32 KB, B/N tile

    const int bm = blockIdx.x;          // x tile: 0..31
    const int bn = blockIdx.y;          // y tile: 0..127
    const int tid  = threadIdx.x;
    const int wave = tid >> 6;          // 0..7
    const int lane = tid & 63;
    const int quad = lane >> 4;
    const int l15  = lane & 15;
    const int wm   = wave & 1;          // y-dim half (64 rows)
    const int wn   = wave >> 1;         // x-dim quarter (32 rows)

    f32x4 acc[4][2];
    #pragma unroll
    for (int i = 0; i < 4; ++i)
        #pragma unroll
        for (int j = 0; j < 2; ++j)
            acc[i][j] = f32x4{0.f, 0.f, 0.f, 0.f};

    // staging geometry: each GLDS round = 512 threads x 16 B = 8 KB = 32 rows.
    // wave covers 4 rows (1024 B); lane -> row base + (lane>>4), slot = lane&15.
    // XOR swizzle: LDS slot s of row r holds global chunk s ^ (r & 15).
    const int srow_in_wave = lane >> 4;            // 0..3
    const int sslot        = lane & 15;            // 16-B chunk slot

    #pragma unroll
    for (int kt = 0; kt < 2; ++kt) {
        if (kt) __syncthreads();
        #pragma unroll
        for (int p = 0; p < 4; ++p) {
            const int r = p * 32 + wave * 4 + srow_in_wave;     // 0..127
            const int c = sslot ^ (r & 15);                     // global chunk
            const size_t goff = (size_t)r * DD + kt * BK + c * 8;
            GLDS(yb + (size_t)(bn * BT) * DD + goff, &lY[(p * 8 + wave) * 512]);
            GLDS(xb + (size_t)(bm * BT) * DD + goff, &lX[(p * 8 + wave) * 512]);
        }
        __syncthreads();

        const int ybase = (wm * 64 + l15) * BK;
        const int xbase = (wn * 32 + l15) * BK;
        #pragma unroll
        for (int kk = 0; kk < 4; ++kk) {
            const int sw = ((kk * 4 + quad) ^ l15) * 8;   // swizzled chunk offset (shorts)
            bf16x8 av[4], bv[2];
            #pragma unroll
            for (int i = 0; i < 4; ++i)
                av[i] = *(const bf16x8*)&lY[ybase + i * 16 * BK + sw];
            #pragma unroll
            for (int j = 0; j < 2; ++j)
                bv[j] = *(const bf16x8*)&lX[xbase + j * 16 * BK + sw];
            #pragma unroll
            for (int i = 0; i < 4; ++i)
                #pragma unroll
                for (int j = 0; j < 2; ++j)
                    acc[i][j] = __builtin_amdgcn_mfma_f32_16x16x32_bf16(
                        av[i], bv[j], acc[i][j], 0, 0, 0);
        }
    }

    // ---- epilogue: d = sqrt(max(x2 + y2 - 2*xy, 0)), float4 stores along y
    const int xr0 = bm * BT + wn * 32;
    const int yc0 = bn * BT + wm * 64;
    #pragma unroll
    for (int i = 0; i < 4; ++i) {
        const int ycol = yc0 + i * 16 + quad * 4;
        const f32x4 ynv = *(const f32x4*)&yn[ycol];
        #pragma unroll
        for (int j = 0; j < 2; ++j) {
            const int xrow = xr0 + j * 16 + l15;
            const float xv = xn[xrow];
            f32x4 d;
            #pragma unroll
            for (int r = 0; r < 4; ++r)
                d[r] = sqrtf(fmaxf(xv + ynv[r] - 2.0f * acc[i][j][r], 0.0f));
            *(f32x4*)&out[(size_t)xrow * NYR + ycol] = d;
        }
    }
}

extern "C" void kernel_launch(void* const* d_in, const int* in_sizes, int n_in,
                              void* d_out, int out_size, void* d_ws, size_t ws_size,
                              hipStream_t stream) {
    const float* x = (const float*)d_in[0];
    const float* y = (const float*)d_in[1];
    float* out = (float*)d_out;

    // ws layout (bytes): xb[0, 2M), yb[2M, 10.25M), xn, yn
    unsigned short* xb = (unsigned short*)d_ws;
    unsigned short* yb = xb + (size_t)NXR * DD;
    float* xn = (float*)(yb + (size_t)NYR * DD);
    float* yn = xn + NXR;

    prep_kernel<<<(NXR + NYR) / 4, 256, 0, stream>>>(x, y, xb, yb, xn, yn);
    dist_kernel<<<dim3(NXR / BT, NYR / BT), 512, 0, stream>>>(xb, yb, xn, yn, out);
}